// Round 1
// baseline (1835.678 us; speedup 1.0000x reference)
//
#include <hip/hip_runtime.h>
#include <stdint.h>
#include <stddef.h>

#define AS1 __attribute__((address_space(1)))
#define AS3 __attribute__((address_space(3)))

typedef __attribute__((ext_vector_type(8))) short bf16x8;   // 8 bf16 = 4 VGPRs
typedef __attribute__((ext_vector_type(4))) float f32x4;

static constexpr int S = 4096, D = 4096, HID = 11008;

__device__ __forceinline__ unsigned short f2bf(float f) {
  unsigned u = __float_as_uint(f);
  u += 0x7FFFu + ((u >> 16) & 1u);       // RNE
  return (unsigned short)(u >> 16);
}

// async global->LDS, 16B per lane; lds dest is wave-uniform base + lane*16
__device__ __forceinline__ void async16(const void* gsrc, void* ldst) {
  __builtin_amdgcn_global_load_lds((AS1 void*)const_cast<void*>(gsrc),
                                   (AS3 void*)ldst, 16, 0, 0);
}

// ---------------- fp32 -> bf16 elementwise (x) ----------------
__global__ __launch_bounds__(256) void k_cvt_bf16(const float* __restrict__ src,
                                                  unsigned short* __restrict__ dst) {
  int i = blockIdx.x * 256 + threadIdx.x;          // 8 elems / thread
  const float4* s = (const float4*)src;
  float4 a = s[2 * i];
  float4 b = s[2 * i + 1];
  union { unsigned short h[8]; uint4 v; } r;
  r.h[0] = f2bf(a.x); r.h[1] = f2bf(a.y); r.h[2] = f2bf(a.z); r.h[3] = f2bf(a.w);
  r.h[4] = f2bf(b.x); r.h[5] = f2bf(b.y); r.h[6] = f2bf(b.z); r.h[7] = f2bf(b.w);
  ((uint4*)dst)[i] = r.v;
}

// ------------- fp32 [R][C] -> bf16 [C][R] transpose+convert -------------
__global__ __launch_bounds__(256) void k_tcvt(const float* __restrict__ src,
                                              unsigned short* __restrict__ dst,
                                              int R, int C) {
  __shared__ float tile[64][65];                    // +1 pad: conflict-free transpose
  const int tid = threadIdx.x;
  const int c0 = blockIdx.x * 64;
  const int r0 = blockIdx.y * 64;
#pragma unroll
  for (int it = 0; it < 16; ++it) {
    int f = it * 256 + tid;
    int r = f >> 6, c = f & 63;
    tile[r][c] = src[(size_t)(r0 + r) * C + (c0 + c)];
  }
  __syncthreads();
#pragma unroll
  for (int it = 0; it < 8; ++it) {
    int f = it * 512 + tid * 2;
    int cc = f >> 6, rr = f & 63;
    unsigned p0 = f2bf(tile[rr][cc]);
    unsigned p1 = f2bf(tile[rr + 1][cc]);
    *(unsigned*)(dst + (size_t)(c0 + cc) * R + (r0 + rr)) = p0 | (p1 << 16);
  }
}

// ------------- GEMM1 fused: gate=x@W1, up=x@W3, h=silu(gate)*up -------------
// A: [S][D] bf16 row-major; B1,B3: [HID][D] bf16 (W^T); Hout: [S][HID] bf16
// Block: 128(M) x 64(N) for BOTH outputs; 4 waves 2x2; wave = 64x32 per output.
__global__ __launch_bounds__(256, 2) void gemm_gateup(
    const unsigned short* __restrict__ A,
    const unsigned short* __restrict__ B1,
    const unsigned short* __restrict__ B3,
    unsigned short* __restrict__ Hout) {
  __shared__ __align__(16) unsigned short sA[128 * 32];   // 8KB
  __shared__ __align__(16) unsigned short sB1[64 * 32];   // 4KB
  __shared__ __align__(16) unsigned short sB3[64 * 32];   // 4KB

  const int tid = threadIdx.x;
  const int wave = tid >> 6, lane = tid & 63;
  const int wy = wave >> 1, wx = wave & 1;
  const int lm = lane & 15, lq = lane >> 4;
  const int m0 = blockIdx.x * 128;
  const int n0 = blockIdx.y * 64;

  // staging geometry: 16B chunk ci -> flat elem ci*8 -> row=ci>>2, col=(ci&3)*8
  const int ci0 = wave * 64 + lane;          // [0,256)
  const int rA0 = ci0 >> 2, cA0 = (ci0 & 3) * 8;
  const int ci1 = ci0 + 256;                 // [256,512) (A only)
  const int rA1 = ci1 >> 2, cA1 = (ci1 & 3) * 8;

  const unsigned short* pA0 = A + (size_t)(m0 + rA0) * D + cA0;
  const unsigned short* pA1 = A + (size_t)(m0 + rA1) * D + cA1;
  const unsigned short* pB1 = B1 + (size_t)(n0 + rA0) * D + cA0;
  const unsigned short* pB3 = B3 + (size_t)(n0 + rA0) * D + cA0;
  unsigned short* lA0 = sA + wave * 512;           // wave-uniform bases
  unsigned short* lA1 = sA + 2048 + wave * 512;
  unsigned short* lB1 = sB1 + wave * 512;
  unsigned short* lB3 = sB3 + wave * 512;

  f32x4 zero = {0.f, 0.f, 0.f, 0.f};
  f32x4 accg[4][2], accu[4][2];
#pragma unroll
  for (int i = 0; i < 4; ++i)
#pragma unroll
    for (int j = 0; j < 2; ++j) { accg[i][j] = zero; accu[i][j] = zero; }

  for (int kt = 0; kt < D / 32; ++kt) {
    __syncthreads();                                  // protect LDS from prev reads
    async16(pA0, lA0);
    async16(pA1, lA1);
    async16(pB1, lB1);
    async16(pB3, lB3);
    pA0 += 32; pA1 += 32; pB1 += 32; pB3 += 32;
    __syncthreads();                                  // implies vmcnt(0) drain

    bf16x8 af[4];
#pragma unroll
    for (int i = 0; i < 4; ++i)
      af[i] = *(const bf16x8*)(sA + (wy * 64 + i * 16 + lm) * 32 + lq * 8);
#pragma unroll
    for (int j = 0; j < 2; ++j) {
      bf16x8 b1f = *(const bf16x8*)(sB1 + (wx * 32 + j * 16 + lm) * 32 + lq * 8);
      bf16x8 b3f = *(const bf16x8*)(sB3 + (wx * 32 + j * 16 + lm) * 32 + lq * 8);
#pragma unroll
      for (int i = 0; i < 4; ++i) {
        accg[i][j] = __builtin_amdgcn_mfma_f32_16x16x32_bf16(af[i], b1f, accg[i][j], 0, 0, 0);
        accu[i][j] = __builtin_amdgcn_mfma_f32_16x16x32_bf16(af[i], b3f, accu[i][j], 0, 0, 0);
      }
    }
  }

  // epilogue: h = silu(g)*u, bf16.  C/D layout: col=lane&15, row=(lane>>4)*4+r
#pragma unroll
  for (int i = 0; i < 4; ++i)
#pragma unroll
    for (int j = 0; j < 2; ++j) {
      int col = n0 + wx * 32 + j * 16 + lm;
#pragma unroll
      for (int r = 0; r < 4; ++r) {
        int row = m0 + wy * 64 + i * 16 + lq * 4 + r;
        float g = accg[i][j][r];
        float u = accu[i][j][r];
        float hv = (g / (1.0f + __expf(-g))) * u;
        Hout[(size_t)row * HID + col] = f2bf(hv);
      }
    }
}

// ------------- GEMM2: out = h @ W2   (A:[S][HID], B:[D][HID]=W2^T, C fp32) -------------
__global__ __launch_bounds__(256, 2) void gemm_out(
    const unsigned short* __restrict__ A,
    const unsigned short* __restrict__ B,
    float* __restrict__ C) {
  __shared__ __align__(16) unsigned short sA[128 * 32];
  __shared__ __align__(16) unsigned short sB[128 * 32];

  const int tid = threadIdx.x;
  const int wave = tid >> 6, lane = tid & 63;
  const int wy = wave >> 1, wx = wave & 1;
  const int lm = lane & 15, lq = lane >> 4;
  const int m0 = blockIdx.x * 128;
  const int n0 = blockIdx.y * 128;

  const int ci0 = wave * 64 + lane;
  const int r0 = ci0 >> 2, c0 = (ci0 & 3) * 8;
  const int ci1 = ci0 + 256;
  const int r1 = ci1 >> 2, c1 = (ci1 & 3) * 8;

  const unsigned short* pA0 = A + (size_t)(m0 + r0) * HID + c0;
  const unsigned short* pA1 = A + (size_t)(m0 + r1) * HID + c1;
  const unsigned short* pB0 = B + (size_t)(n0 + r0) * HID + c0;
  const unsigned short* pB1 = B + (size_t)(n0 + r1) * HID + c1;
  unsigned short* lA0 = sA + wave * 512;
  unsigned short* lA1 = sA + 2048 + wave * 512;
  unsigned short* lB0 = sB + wave * 512;
  unsigned short* lB1 = sB + 2048 + wave * 512;

  f32x4 zero = {0.f, 0.f, 0.f, 0.f};
  f32x4 acc[4][4];
#pragma unroll
  for (int i = 0; i < 4; ++i)
#pragma unroll
    for (int j = 0; j < 4; ++j) acc[i][j] = zero;

  for (int kt = 0; kt < HID / 32; ++kt) {
    __syncthreads();
    async16(pA0, lA0);
    async16(pA1, lA1);
    async16(pB0, lB0);
    async16(pB1, lB1);
    pA0 += 32; pA1 += 32; pB0 += 32; pB1 += 32;
    __syncthreads();

    bf16x8 af[4];
#pragma unroll
    for (int i = 0; i < 4; ++i)
      af[i] = *(const bf16x8*)(sA + (wy * 64 + i * 16 + lm) * 32 + lq * 8);
#pragma unroll
    for (int j = 0; j < 4; ++j) {
      bf16x8 bfj = *(const bf16x8*)(sB + (wx * 64 + j * 16 + lm) * 32 + lq * 8);
#pragma unroll
      for (int i = 0; i < 4; ++i)
        acc[i][j] = __builtin_amdgcn_mfma_f32_16x16x32_bf16(af[i], bfj, acc[i][j], 0, 0, 0);
    }
  }

#pragma unroll
  for (int i = 0; i < 4; ++i)
#pragma unroll
    for (int j = 0; j < 4; ++j) {
      int col = n0 + wx * 64 + j * 16 + lm;
#pragma unroll
      for (int r = 0; r < 4; ++r) {
        int row = m0 + wy * 64 + i * 16 + lq * 4 + r;
        C[(size_t)row * D + col] = acc[i][j][r];
      }
    }
}

extern "C" void kernel_launch(void* const* d_in, const int* in_sizes, int n_in,
                              void* d_out, int out_size, void* d_ws, size_t ws_size,
                              hipStream_t stream) {
  const float* x  = (const float*)d_in[0];   // [S][D]
  const float* w1 = (const float*)d_in[1];   // [D][HID]
  const float* w2 = (const float*)d_in[2];   // [HID][D]
  const float* w3 = (const float*)d_in[3];   // [D][HID]
  float* out = (float*)d_out;                // [S][D]

  char* ws = (char*)d_ws;
  // layout (bytes): xb 33,554,432 | w1t 90,177,536 | w3t 90,177,536 | h 90,177,536
  unsigned short* xb   = (unsigned short*)(ws);
  unsigned short* w1t  = (unsigned short*)(ws + (size_t)33554432);
  unsigned short* w3t  = (unsigned short*)(ws + (size_t)123731968);
  unsigned short* hbuf = (unsigned short*)(ws + (size_t)213909504);
  unsigned short* w2t  = w1t;   // W2^T reuses W1^T region after gemm_gateup

  k_cvt_bf16<<<dim3((S * D) / 8 / 256), 256, 0, stream>>>(x, xb);
  k_tcvt<<<dim3(HID / 64, D / 64), 256, 0, stream>>>(w1, w1t, D, HID);
  k_tcvt<<<dim3(HID / 64, D / 64), 256, 0, stream>>>(w3, w3t, D, HID);
  gemm_gateup<<<dim3(S / 128, HID / 64), 256, 0, stream>>>(xb, w1t, w3t, hbuf);
  k_tcvt<<<dim3(D / 64, HID / 64), 256, 0, stream>>>(w2, w2t, HID, D);
  gemm_out<<<dim3(S / 128, D / 128), 256, 0, stream>>>(hbuf, w2t, out);
}